// Round 1
// baseline (1111.959 us; speedup 1.0000x reference)
//
#include <hip/hip_runtime.h>
#include <math.h>

#define EPSF 1e-6f

constexpr int B_  = 2;
constexpr int L_  = 1024;
constexpr int D_  = 512;
constexpr int H_  = 8;
constexpr int DH_ = 64;
constexpr int BL_ = B_ * L_;   // 2048
constexpr int BH_ = B_ * H_;   // 16
constexpr int CT_ = 64;        // attention chunk length
constexpr int NC_ = L_ / CT_;  // 16 chunks

// ---------------------------------------------------------------------------
// Tiled fp32 GEMM: out[M,N] = A[M,512] @ W[512,N] + bias, optional sigmoid,
// optional permuted store into [B,H,L,Dh] layout.
// Grid: (M/64, N/64), 256 threads, 4x4 microtile.
// ---------------------------------------------------------------------------
template <bool SIG, bool PERM>
__global__ __launch_bounds__(256) void gemm_k(const float* __restrict__ A,
                                              const float* __restrict__ W,
                                              const float* __restrict__ bias,
                                              float* __restrict__ out) {
  __shared__ float As[16][64];  // [k][row]
  __shared__ float Bs[16][64];  // [k][col]
  const int tid = threadIdx.x;
  const int m0 = blockIdx.x * 64, n0 = blockIdx.y * 64;
  const int tx = tid & 15, ty = tid >> 4;
  const int ar = tid >> 2, ak4 = (tid & 3) << 2;   // A stage: row, k-quad
  const int bk = tid >> 4, bn4 = (tid & 15) << 2;  // B stage: k, col-quad
  float acc[4][4] = {};
  for (int kt = 0; kt < D_; kt += 16) {
    const float4 av = *(const float4*)&A[(size_t)(m0 + ar) * D_ + kt + ak4];
    const float4 bv = *(const float4*)&W[(size_t)(kt + bk) * D_ + n0 + bn4];
    __syncthreads();
    As[ak4 + 0][ar] = av.x;
    As[ak4 + 1][ar] = av.y;
    As[ak4 + 2][ar] = av.z;
    As[ak4 + 3][ar] = av.w;
    *(float4*)&Bs[bk][bn4] = bv;
    __syncthreads();
#pragma unroll
    for (int kk = 0; kk < 16; ++kk) {
      const float4 a = *(const float4*)&As[kk][ty * 4];
      const float4 b = *(const float4*)&Bs[kk][tx * 4];
      acc[0][0] += a.x * b.x; acc[0][1] += a.x * b.y; acc[0][2] += a.x * b.z; acc[0][3] += a.x * b.w;
      acc[1][0] += a.y * b.x; acc[1][1] += a.y * b.y; acc[1][2] += a.y * b.z; acc[1][3] += a.y * b.w;
      acc[2][0] += a.z * b.x; acc[2][1] += a.z * b.y; acc[2][2] += a.z * b.z; acc[2][3] += a.z * b.w;
      acc[3][0] += a.w * b.x; acc[3][1] += a.w * b.y; acc[3][2] += a.w * b.z; acc[3][3] += a.w * b.w;
    }
  }
  const float4 bb4 = *(const float4*)&bias[n0 + tx * 4];
  const float bias4[4] = {bb4.x, bb4.y, bb4.z, bb4.w};
#pragma unroll
  for (int i = 0; i < 4; ++i) {
    const int r = m0 + ty * 4 + i;
    float4 v;
    float* vp = (float*)&v;
#pragma unroll
    for (int j = 0; j < 4; ++j) {
      float x = acc[i][j] + bias4[j];
      if (SIG) x = 1.0f / (1.0f + expf(-x));
      vp[j] = x;
    }
    if (PERM) {
      // row r -> (b, l); col -> (h, dh). Store [B,H,L,Dh].
      const int b = r >> 10, l = r & (L_ - 1);
      const int h = n0 >> 6, dh0 = tx * 4;
      *(float4*)&out[(((size_t)(b * H_ + h)) * L_ + l) * DH_ + dh0] = v;
    } else {
      *(float4*)&out[(size_t)r * D_ + n0 + tx * 4] = v;
    }
  }
}

// ---------------------------------------------------------------------------
// Scalar flow pass: per (b,h) sequential scan over l computing
// qscale = 1/denq, sink_allocation, source_competition.
// One wave per (b,h); lane = d.
// ---------------------------------------------------------------------------
__global__ __launch_bounds__(64) void flow_scalar_k(const float* __restrict__ Q,
                                                    const float* __restrict__ K,
                                                    float* __restrict__ qscale,
                                                    float* __restrict__ salloc,
                                                    float* __restrict__ comp) {
  const int bh = blockIdx.x;
  const int lane = threadIdx.x;
  const float* q = Q + (size_t)bh * L_ * DH_;
  const float* k = K + (size_t)bh * L_ * DH_;
  float cumk = 0.f, cumq = 0.f, cumkso = 0.f, cumqsi = 0.f, cume = 0.f;
  for (int l = 0; l < L_; ++l) {
    const float ql = q[l * DH_ + lane];
    const float kl = k[l * DH_ + lane];
    cumk += kl;
    cumq += ql;
    const float qe = ql + EPSF, ke = kl + EPSF;
    float a = qe * (cumk + EPSF);
    float b = ke * (cumq + EPSF);
#pragma unroll
    for (int off = 32; off; off >>= 1) {
      a += __shfl_xor(a, off);
      b += __shfl_xor(b, off);
    }
    const float normal = (float)(l + 1);
    const float si = normal / a;  // sink_incoming
    const float so = normal / b;  // source_outgoing
    cumkso += kl * so;
    cumqsi += ql * si;
    float c1 = qe * (cumkso + EPSF);
    float c2 = ke * (cumqsi + EPSF);
#pragma unroll
    for (int off = 32; off; off >>= 1) {
      c1 += __shfl_xor(c1, off);
      c2 += __shfl_xor(c2, off);
    }
    const float cs_sink = c1 / normal;
    float cs_src = c2 / normal;
    cs_src = fminf(1.0f, fmaxf(-1.0f, cs_src));
    const float e = expf(cs_src);
    cume += e;
    if (lane == 0) {
      qscale[bh * L_ + l] = 1.0f / a;                       // si / normal
      salloc[bh * L_ + l] = 1.0f / (1.0f + expf(-cs_sink)); // sigmoid(conserved_sink)
      comp[bh * L_ + l] = e / cume * normal;                // source_competition
    }
  }
}

// ---------------------------------------------------------------------------
// Chunk-local KV sums: KV[bc][d][m] = sum_{l in chunk} k[l,d] * (v[l,m]*comp[l])
// Grid: BH*NC blocks, 256 threads.
// ---------------------------------------------------------------------------
__global__ __launch_bounds__(256) void chunk_kv_k(const float* __restrict__ K,
                                                  const float* __restrict__ V,
                                                  const float* __restrict__ comp,
                                                  float* __restrict__ KV) {
  const int bc = blockIdx.x;   // bh*NC + c
  const int g = bc * CT_;      // == bh*L + c*CT
  const float* k = K + (size_t)g * DH_;
  const float* v = V + (size_t)g * DH_;
  __shared__ float kb[CT_][DH_];
  __shared__ float vb[CT_][DH_];
  const int tid = threadIdx.x;
  for (int i = tid; i < CT_ * DH_; i += 256) {
    const int l = i >> 6;
    kb[l][i & 63] = k[i];
    vb[l][i & 63] = v[i] * comp[g + l];
  }
  __syncthreads();
  const int m = tid & 63, dg = tid >> 6;  // wave dg owns d in [dg*16, dg*16+16)
  float acc[16] = {};
  for (int l = 0; l < CT_; ++l) {
    const float vm = vb[l][m];
#pragma unroll
    for (int i = 0; i < 16; ++i) acc[i] += kb[l][dg * 16 + i] * vm;
  }
  float* out = KV + ((size_t)bc * DH_ + dg * 16) * DH_ + m;
#pragma unroll
  for (int i = 0; i < 16; ++i) out[i * DH_] = acc[i];
}

// ---------------------------------------------------------------------------
// In-place exclusive prefix over chunks of KV. Grid: BH blocks, 256 threads.
// ---------------------------------------------------------------------------
__global__ __launch_bounds__(256) void kv_prefix_k(float* __restrict__ KV) {
  const int bh = blockIdx.x;
  const int tid = threadIdx.x;
  for (int p = tid; p < DH_ * DH_; p += 256) {
    float run = 0.f;
    const size_t base = (size_t)bh * NC_ * DH_ * DH_ + p;
#pragma unroll
    for (int c = 0; c < NC_; ++c) {
      const float t = KV[base + (size_t)c * DH_ * DH_];
      KV[base + (size_t)c * DH_ * DH_] = run;
      run += t;
    }
  }
}

// ---------------------------------------------------------------------------
// Per-chunk attention: out[l] = (qp[l] @ KVprefix + tril(qp k^T) v') * salloc[l]
// Grid: BH*NC blocks, 256 threads.
// ---------------------------------------------------------------------------
__global__ __launch_bounds__(256) void attn_k(const float* __restrict__ Q,
                                              const float* __restrict__ K,
                                              const float* __restrict__ V,
                                              const float* __restrict__ KV,
                                              const float* __restrict__ qscale,
                                              const float* __restrict__ salloc,
                                              const float* __restrict__ comp,
                                              float* __restrict__ X) {
  const int bc = blockIdx.x;
  const int bh = bc >> 4, c = bc & (NC_ - 1);
  const int bb = bh >> 3, hh = bh & (H_ - 1);
  const int g = bc * CT_;  // bh*L + c*CT
  __shared__ float qp[CT_][DH_ + 4];  // padded: lane-strided float4 reads
  __shared__ float kb[CT_][DH_];      // broadcast reads only
  __shared__ float S[CT_][CT_ + 4];   // scores, padded
  const int tid = threadIdx.x;
  for (int i = tid; i < CT_ * DH_; i += 256) {
    const int l = i >> 6, d = i & 63;
    qp[l][d] = Q[(size_t)g * DH_ + i] * qscale[g + l];
    kb[l][d] = K[(size_t)g * DH_ + i];
  }
  __syncthreads();
  const int m = tid & 63, w = tid >> 6;
  float acc[16] = {};
  // Phase 1: inter-chunk  acc[i] += qp[w*16+i] . KVprefix[:, m]
  const float* kvp = KV + (size_t)bc * DH_ * DH_;
  for (int d4 = 0; d4 < 16; ++d4) {
    float kvv[4];
#pragma unroll
    for (int e = 0; e < 4; ++e) kvv[e] = kvp[(d4 * 4 + e) * DH_ + m];
#pragma unroll
    for (int i = 0; i < 16; ++i) {
      const float4 q4 = *(const float4*)&qp[w * 16 + i][d4 * 4];
      acc[i] += q4.x * kvv[0] + q4.y * kvv[1] + q4.z * kvv[2] + q4.w * kvv[3];
    }
  }
  // Phase 2: scores S[l][j] = (j<=l) ? qp[l].kb[j] : 0   (lane = l, j = w*16+i)
  {
    float sc[16] = {};
    for (int d4 = 0; d4 < 16; ++d4) {
      const float4 q4 = *(const float4*)&qp[m][d4 * 4];
#pragma unroll
      for (int i = 0; i < 16; ++i) {
        const float4 k4 = *(const float4*)&kb[w * 16 + i][d4 * 4];
        sc[i] += q4.x * k4.x + q4.y * k4.y + q4.z * k4.z + q4.w * k4.w;
      }
    }
#pragma unroll
    for (int i = 0; i < 16; ++i) {
      const int j = w * 16 + i;
      S[m][j] = (j <= m) ? sc[i] : 0.0f;
    }
  }
  __syncthreads();
  // Phase 3: intra-chunk  acc[i] += sum_j S[l][j] * v'[j][m]
  for (int j4 = 0; j4 < 16; ++j4) {
    float vv[4];
#pragma unroll
    for (int e = 0; e < 4; ++e) {
      const int j = j4 * 4 + e;
      vv[e] = V[(size_t)(g + j) * DH_ + m] * comp[g + j];
    }
#pragma unroll
    for (int i = 0; i < 16; ++i) {
      const float4 s4 = *(const float4*)&S[w * 16 + i][j4 * 4];
      acc[i] += s4.x * vv[0] + s4.y * vv[1] + s4.z * vv[2] + s4.w * vv[3];
    }
  }
  // Epilogue: * sink_allocation, store X in [B, L, H*Dh]
#pragma unroll
  for (int i = 0; i < 16; ++i) {
    const int l = w * 16 + i;
    X[((size_t)(bb * L_ + c * CT_ + l)) * D_ + hh * DH_ + m] = acc[i] * salloc[g + l];
  }
}

// ---------------------------------------------------------------------------
extern "C" void kernel_launch(void* const* d_in, const int* in_sizes, int n_in,
                              void* d_out, int out_size, void* d_ws, size_t ws_size,
                              hipStream_t stream) {
  (void)in_sizes; (void)n_in; (void)out_size; (void)ws_size;
  const float* queries = (const float*)d_in[0];
  const float* keys    = (const float*)d_in[1];
  const float* values  = (const float*)d_in[2];
  const float* Wq = (const float*)d_in[3];
  const float* bq = (const float*)d_in[4];
  const float* Wk = (const float*)d_in[5];
  const float* bk = (const float*)d_in[6];
  const float* Wv = (const float*)d_in[7];
  const float* bv = (const float*)d_in[8];
  const float* Wo = (const float*)d_in[9];
  const float* bo = (const float*)d_in[10];

  float* ws = (float*)d_ws;
  const size_t seg = (size_t)BH_ * L_ * DH_;  // 1,048,576 floats
  float* Qb  = ws;
  float* Kb  = Qb + seg;
  float* Vb  = Kb + seg;
  float* Xb  = Vb + seg;                       // [BL, D]
  float* KVb = Xb + (size_t)BL_ * D_;          // [BH, NC, DH, DH]
  float* qscale = KVb + (size_t)BH_ * NC_ * DH_ * DH_;
  float* salloc = qscale + BH_ * L_;
  float* comp   = salloc + BH_ * L_;

  const dim3 gg(BL_ / 64, D_ / 64);
  gemm_k<true,  true ><<<gg, 256, 0, stream>>>(queries, Wq, bq, Qb);
  gemm_k<true,  true ><<<gg, 256, 0, stream>>>(keys,    Wk, bk, Kb);
  gemm_k<false, true ><<<gg, 256, 0, stream>>>(values,  Wv, bv, Vb);
  flow_scalar_k<<<BH_, 64, 0, stream>>>(Qb, Kb, qscale, salloc, comp);
  chunk_kv_k<<<BH_ * NC_, 256, 0, stream>>>(Kb, Vb, comp, KVb);
  kv_prefix_k<<<BH_, 256, 0, stream>>>(KVb);
  attn_k<<<BH_ * NC_, 256, 0, stream>>>(Qb, Kb, Vb, KVb, qscale, salloc, comp, Xb);
  gemm_k<false, false><<<gg, 256, 0, stream>>>(Xb, Wo, bo, (float*)d_out);
}

// Round 2
// 226.431 us; speedup vs baseline: 4.9108x; 4.9108x over previous
//
#include <hip/hip_runtime.h>
#include <math.h>

#define EPSF 1e-6f

constexpr int B_  = 2;
constexpr int L_  = 1024;
constexpr int D_  = 512;
constexpr int H_  = 8;
constexpr int DH_ = 64;
constexpr int BL_ = B_ * L_;   // 2048
constexpr int BH_ = B_ * H_;   // 16
constexpr int CT_ = 64;        // chunk length (flow + attention)
constexpr int NC_ = L_ / CT_;  // 16 chunks

// ---------------------------------------------------------------------------
// Tiled fp32 GEMM: out[M,N] = A[M,512] @ W[512,N] + bias, optional sigmoid,
// optional permuted store into [B,H,L,Dh] layout.
// ---------------------------------------------------------------------------
template <bool SIG, bool PERM>
__global__ __launch_bounds__(256) void gemm_k(const float* __restrict__ A,
                                              const float* __restrict__ W,
                                              const float* __restrict__ bias,
                                              float* __restrict__ out) {
  __shared__ float As[16][64];  // [k][row]
  __shared__ float Bs[16][64];  // [k][col]
  const int tid = threadIdx.x;
  const int m0 = blockIdx.x * 64, n0 = blockIdx.y * 64;
  const int tx = tid & 15, ty = tid >> 4;
  const int ar = tid >> 2, ak4 = (tid & 3) << 2;
  const int bk = tid >> 4, bn4 = (tid & 15) << 2;
  float acc[4][4] = {};
  for (int kt = 0; kt < D_; kt += 16) {
    const float4 av = *(const float4*)&A[(size_t)(m0 + ar) * D_ + kt + ak4];
    const float4 bv = *(const float4*)&W[(size_t)(kt + bk) * D_ + n0 + bn4];
    __syncthreads();
    As[ak4 + 0][ar] = av.x;
    As[ak4 + 1][ar] = av.y;
    As[ak4 + 2][ar] = av.z;
    As[ak4 + 3][ar] = av.w;
    *(float4*)&Bs[bk][bn4] = bv;
    __syncthreads();
#pragma unroll
    for (int kk = 0; kk < 16; ++kk) {
      const float4 a = *(const float4*)&As[kk][ty * 4];
      const float4 b = *(const float4*)&Bs[kk][tx * 4];
      acc[0][0] += a.x * b.x; acc[0][1] += a.x * b.y; acc[0][2] += a.x * b.z; acc[0][3] += a.x * b.w;
      acc[1][0] += a.y * b.x; acc[1][1] += a.y * b.y; acc[1][2] += a.y * b.z; acc[1][3] += a.y * b.w;
      acc[2][0] += a.z * b.x; acc[2][1] += a.z * b.y; acc[2][2] += a.z * b.z; acc[2][3] += a.z * b.w;
      acc[3][0] += a.w * b.x; acc[3][1] += a.w * b.y; acc[3][2] += a.w * b.z; acc[3][3] += a.w * b.w;
    }
  }
  const float4 bb4 = *(const float4*)&bias[n0 + tx * 4];
  const float bias4[4] = {bb4.x, bb4.y, bb4.z, bb4.w};
#pragma unroll
  for (int i = 0; i < 4; ++i) {
    const int r = m0 + ty * 4 + i;
    float4 v;
    float* vp = (float*)&v;
#pragma unroll
    for (int j = 0; j < 4; ++j) {
      float x = acc[i][j] + bias4[j];
      if (SIG) x = 1.0f / (1.0f + expf(-x));
      vp[j] = x;
    }
    if (PERM) {
      const int b = r >> 10, l = r & (L_ - 1);
      const int h = n0 >> 6, dh0 = tx * 4;
      *(float4*)&out[(((size_t)(b * H_ + h)) * L_ + l) * DH_ + dh0] = v;
    } else {
      *(float4*)&out[(size_t)r * D_ + n0 + tx * 4] = v;
    }
  }
}

// ---------------------------------------------------------------------------
// Flow pass, chunk-parallel.  bc = bh*NC + c;  rows g = bc*CT (== bh*L + c*CT).
// ---------------------------------------------------------------------------

// FA: per-chunk column sums of Q and K. grid BH*NC, 64 thr, lane = d.
__global__ __launch_bounds__(64) void flow_chunksum_k(const float* __restrict__ Q,
                                                      const float* __restrict__ K,
                                                      float* __restrict__ sumQ,
                                                      float* __restrict__ sumK) {
  const int bc = blockIdx.x, d = threadIdx.x;
  const float* q = Q + (size_t)bc * CT_ * DH_;
  const float* k = K + (size_t)bc * CT_ * DH_;
  float sq = 0.f, sk = 0.f;
  for (int l = 0; l < CT_; ++l) { sq += q[l * DH_ + d]; sk += k[l * DH_ + d]; }
  sumQ[bc * DH_ + d] = sq;
  sumK[bc * DH_ + d] = sk;
}

// FB: exclusive prefix over chunks (vector of 64 dims). grid BH, 64 thr.
__global__ __launch_bounds__(64) void flow_prefix2_k(const float* __restrict__ sA,
                                                     const float* __restrict__ sB,
                                                     float* __restrict__ pA,
                                                     float* __restrict__ pB) {
  const int bh = blockIdx.x, d = threadIdx.x;
  float ra = 0.f, rb = 0.f;
  for (int c = 0; c < NC_; ++c) {
    const int i = (bh * NC_ + c) * DH_ + d;
    pA[i] = ra; pB[i] = rb;
    ra += sA[i]; rb += sB[i];
  }
}

// FC: phase 1 — a,b via per-d wave scans; outputs qscale, si, so and chunk
// sums of q*si, k*so. grid BH*NC, 64 thr, lane = l.
__global__ __launch_bounds__(64) void flow_phase1_k(const float* __restrict__ Q,
                                                    const float* __restrict__ K,
                                                    const float* __restrict__ prefQ,
                                                    const float* __restrict__ prefK,
                                                    float* __restrict__ qscale,
                                                    float* __restrict__ si_a,
                                                    float* __restrict__ so_a,
                                                    float* __restrict__ sumQSI,
                                                    float* __restrict__ sumKSO) {
  const int bc = blockIdx.x, c = bc & (NC_ - 1);
  const int lane = threadIdx.x;
  const int g = bc * CT_;
  __shared__ float qS[CT_][DH_ + 1];
  __shared__ float kS[CT_][DH_ + 1];
  for (int i = lane; i < CT_ * DH_; i += 64) {
    const int l = i >> 6, d = i & 63;
    qS[l][d] = Q[(size_t)g * DH_ + i];
    kS[l][d] = K[(size_t)g * DH_ + i];
  }
  __syncthreads();
  const int base = bc * DH_;
  float a = 0.f, b = 0.f;
  for (int d = 0; d < DH_; ++d) {
    const float qv = qS[lane][d];
    const float kv = kS[lane][d];
    float ck = kv, cq = qv;
#pragma unroll
    for (int off = 1; off < 64; off <<= 1) {
      const float t1 = __shfl_up(ck, off);
      const float t2 = __shfl_up(cq, off);
      ck += (lane >= off) ? t1 : 0.f;
      cq += (lane >= off) ? t2 : 0.f;
    }
    ck += prefK[base + d];
    cq += prefQ[base + d];
    a += (qv + EPSF) * (ck + EPSF);
    b += (kv + EPSF) * (cq + EPSF);
  }
  const float normal = (float)(c * CT_ + lane + 1);
  const float si = normal / a, so = normal / b;
  qscale[g + lane] = 1.0f / a;
  si_a[g + lane] = si;
  so_a[g + lane] = so;
  // chunk sums of q*si, k*so (switch lane role to d; broadcast si/so via shfl)
  float sqsi = 0.f, skso = 0.f;
  for (int l = 0; l < CT_; ++l) {
    const float sil = __shfl(si, l);
    const float sol = __shfl(so, l);
    sqsi += qS[l][lane] * sil;
    skso += kS[l][lane] * sol;
  }
  sumQSI[base + lane] = sqsi;
  sumKSO[base + lane] = skso;
}

// FE: phase 2 — conserved sink/source, salloc, e=exp(clip), chunk sum of e.
__global__ __launch_bounds__(64) void flow_phase2_k(const float* __restrict__ Q,
                                                    const float* __restrict__ K,
                                                    const float* __restrict__ prefQSI,
                                                    const float* __restrict__ prefKSO,
                                                    const float* __restrict__ si_a,
                                                    const float* __restrict__ so_a,
                                                    float* __restrict__ salloc,
                                                    float* __restrict__ e_a,
                                                    float* __restrict__ sumE) {
  const int bc = blockIdx.x, c = bc & (NC_ - 1);
  const int lane = threadIdx.x;
  const int g = bc * CT_;
  __shared__ float qS[CT_][DH_ + 1];
  __shared__ float kS[CT_][DH_ + 1];
  for (int i = lane; i < CT_ * DH_; i += 64) {
    const int l = i >> 6, d = i & 63;
    qS[l][d] = Q[(size_t)g * DH_ + i];
    kS[l][d] = K[(size_t)g * DH_ + i];
  }
  __syncthreads();
  const float si = si_a[g + lane];
  const float so = so_a[g + lane];
  const int base = bc * DH_;
  float c1 = 0.f, c2 = 0.f;
  for (int d = 0; d < DH_; ++d) {
    const float qv = qS[lane][d];
    const float kv = kS[lane][d];
    float ckso = kv * so, cqsi = qv * si;
#pragma unroll
    for (int off = 1; off < 64; off <<= 1) {
      const float t1 = __shfl_up(ckso, off);
      const float t2 = __shfl_up(cqsi, off);
      ckso += (lane >= off) ? t1 : 0.f;
      cqsi += (lane >= off) ? t2 : 0.f;
    }
    ckso += prefKSO[base + d];
    cqsi += prefQSI[base + d];
    c1 += (qv + EPSF) * (ckso + EPSF);
    c2 += (kv + EPSF) * (cqsi + EPSF);
  }
  const float normal = (float)(c * CT_ + lane + 1);
  const float cs_sink = c1 / normal;
  salloc[g + lane] = 1.0f / (1.0f + expf(-cs_sink));
  float cs_src = c2 / normal;
  cs_src = fminf(1.0f, fmaxf(-1.0f, cs_src));
  const float e = expf(cs_src);
  e_a[g + lane] = e;
  float tot = e;
#pragma unroll
  for (int off = 32; off; off >>= 1) tot += __shfl_xor(tot, off);
  if (lane == 0) sumE[bc] = tot;
}

// FF: scalar exclusive prefix of chunk e-sums. grid 1, 16 thr (t = bh).
__global__ void flow_prefixE_k(const float* __restrict__ sumE, float* __restrict__ prefE) {
  const int bh = threadIdx.x;
  if (bh >= BH_) return;
  float r = 0.f;
  for (int c = 0; c < NC_; ++c) {
    prefE[bh * NC_ + c] = r;
    r += sumE[bh * NC_ + c];
  }
}

// FG: source_competition. grid BH*NC, 64 thr, lane = l.
__global__ __launch_bounds__(64) void flow_comp_k(const float* __restrict__ e_a,
                                                  const float* __restrict__ prefE,
                                                  float* __restrict__ comp) {
  const int bc = blockIdx.x, c = bc & (NC_ - 1);
  const int lane = threadIdx.x;
  const int g = bc * CT_;
  const float e = e_a[g + lane];
  float s = e;
#pragma unroll
  for (int off = 1; off < 64; off <<= 1) {
    const float t = __shfl_up(s, off);
    s += (lane >= off) ? t : 0.f;
  }
  const float cume = prefE[bc] + s;
  comp[g + lane] = e / cume * (float)(c * CT_ + lane + 1);
}

// ---------------------------------------------------------------------------
// Chunk-local KV sums: KV[bc][d][m] = sum_{l in chunk} k[l,d] * (v[l,m]*comp[l])
// ---------------------------------------------------------------------------
__global__ __launch_bounds__(256) void chunk_kv_k(const float* __restrict__ K,
                                                  const float* __restrict__ V,
                                                  const float* __restrict__ comp,
                                                  float* __restrict__ KV) {
  const int bc = blockIdx.x;
  const int g = bc * CT_;
  const float* k = K + (size_t)g * DH_;
  const float* v = V + (size_t)g * DH_;
  __shared__ float kb[CT_][DH_];
  __shared__ float vb[CT_][DH_];
  const int tid = threadIdx.x;
  for (int i = tid; i < CT_ * DH_; i += 256) {
    const int l = i >> 6;
    kb[l][i & 63] = k[i];
    vb[l][i & 63] = v[i] * comp[g + l];
  }
  __syncthreads();
  const int m = tid & 63, dg = tid >> 6;
  float acc[16] = {};
  for (int l = 0; l < CT_; ++l) {
    const float vm = vb[l][m];
#pragma unroll
    for (int i = 0; i < 16; ++i) acc[i] += kb[l][dg * 16 + i] * vm;
  }
  float* out = KV + ((size_t)bc * DH_ + dg * 16) * DH_ + m;
#pragma unroll
  for (int i = 0; i < 16; ++i) out[i * DH_] = acc[i];
}

// In-place exclusive prefix over chunks of KV. grid BH, 256 thr.
__global__ __launch_bounds__(256) void kv_prefix_k(float* __restrict__ KV) {
  const int bh = blockIdx.x;
  const int tid = threadIdx.x;
  for (int p = tid; p < DH_ * DH_; p += 256) {
    float run = 0.f;
    const size_t base = (size_t)bh * NC_ * DH_ * DH_ + p;
#pragma unroll
    for (int c = 0; c < NC_; ++c) {
      const float t = KV[base + (size_t)c * DH_ * DH_];
      KV[base + (size_t)c * DH_ * DH_] = run;
      run += t;
    }
  }
}

// Per-chunk attention: out = (qp @ KVprefix + tril(qp k^T) v') * salloc
__global__ __launch_bounds__(256) void attn_k(const float* __restrict__ Q,
                                              const float* __restrict__ K,
                                              const float* __restrict__ V,
                                              const float* __restrict__ KV,
                                              const float* __restrict__ qscale,
                                              const float* __restrict__ salloc,
                                              const float* __restrict__ comp,
                                              float* __restrict__ X) {
  const int bc = blockIdx.x;
  const int bh = bc >> 4, c = bc & (NC_ - 1);
  const int bb = bh >> 3, hh = bh & (H_ - 1);
  const int g = bc * CT_;
  __shared__ float qp[CT_][DH_ + 4];
  __shared__ float kb[CT_][DH_];
  __shared__ float S[CT_][CT_ + 4];
  const int tid = threadIdx.x;
  for (int i = tid; i < CT_ * DH_; i += 256) {
    const int l = i >> 6, d = i & 63;
    qp[l][d] = Q[(size_t)g * DH_ + i] * qscale[g + l];
    kb[l][d] = K[(size_t)g * DH_ + i];
  }
  __syncthreads();
  const int m = tid & 63, w = tid >> 6;
  float acc[16] = {};
  const float* kvp = KV + (size_t)bc * DH_ * DH_;
  for (int d4 = 0; d4 < 16; ++d4) {
    float kvv[4];
#pragma unroll
    for (int e = 0; e < 4; ++e) kvv[e] = kvp[(d4 * 4 + e) * DH_ + m];
#pragma unroll
    for (int i = 0; i < 16; ++i) {
      const float4 q4 = *(const float4*)&qp[w * 16 + i][d4 * 4];
      acc[i] += q4.x * kvv[0] + q4.y * kvv[1] + q4.z * kvv[2] + q4.w * kvv[3];
    }
  }
  {
    float sc[16] = {};
    for (int d4 = 0; d4 < 16; ++d4) {
      const float4 q4 = *(const float4*)&qp[m][d4 * 4];
#pragma unroll
      for (int i = 0; i < 16; ++i) {
        const float4 k4 = *(const float4*)&kb[w * 16 + i][d4 * 4];
        sc[i] += q4.x * k4.x + q4.y * k4.y + q4.z * k4.z + q4.w * k4.w;
      }
    }
#pragma unroll
    for (int i = 0; i < 16; ++i) {
      const int j = w * 16 + i;
      S[m][j] = (j <= m) ? sc[i] : 0.0f;
    }
  }
  __syncthreads();
  for (int j4 = 0; j4 < 16; ++j4) {
    float vv[4];
#pragma unroll
    for (int e = 0; e < 4; ++e) {
      const int j = j4 * 4 + e;
      vv[e] = V[(size_t)(g + j) * DH_ + m] * comp[g + j];
    }
#pragma unroll
    for (int i = 0; i < 16; ++i) {
      const float4 s4 = *(const float4*)&S[w * 16 + i][j4 * 4];
      acc[i] += s4.x * vv[0] + s4.y * vv[1] + s4.z * vv[2] + s4.w * vv[3];
    }
  }
#pragma unroll
  for (int i = 0; i < 16; ++i) {
    const int l = w * 16 + i;
    X[((size_t)(bb * L_ + c * CT_ + l)) * D_ + hh * DH_ + m] = acc[i] * salloc[g + l];
  }
}

// ---------------------------------------------------------------------------
extern "C" void kernel_launch(void* const* d_in, const int* in_sizes, int n_in,
                              void* d_out, int out_size, void* d_ws, size_t ws_size,
                              hipStream_t stream) {
  (void)in_sizes; (void)n_in; (void)out_size; (void)ws_size;
  const float* queries = (const float*)d_in[0];
  const float* keys    = (const float*)d_in[1];
  const float* values  = (const float*)d_in[2];
  const float* Wq = (const float*)d_in[3];
  const float* bq = (const float*)d_in[4];
  const float* Wk = (const float*)d_in[5];
  const float* bk = (const float*)d_in[6];
  const float* Wv = (const float*)d_in[7];
  const float* bv = (const float*)d_in[8];
  const float* Wo = (const float*)d_in[9];
  const float* bo = (const float*)d_in[10];

  float* ws = (float*)d_ws;
  const size_t seg = (size_t)BH_ * L_ * DH_;  // 1,048,576 floats
  float* Qb  = ws;
  float* Kb  = Qb + seg;
  float* Vb  = Kb + seg;
  float* Xb  = Vb + seg;                       // [BL, D]
  float* KVb = Xb + (size_t)BL_ * D_;          // [BH, NC, DH, DH]
  float* p   = KVb + (size_t)BH_ * NC_ * DH_ * DH_;
  float* qscale = p; p += BH_ * L_;
  float* salloc = p; p += BH_ * L_;
  float* comp   = p; p += BH_ * L_;
  float* si_a   = p; p += BH_ * L_;
  float* so_a   = p; p += BH_ * L_;
  float* e_a    = p; p += BH_ * L_;
  float* sumQ   = p; p += BH_ * NC_ * DH_;
  float* sumK   = p; p += BH_ * NC_ * DH_;
  float* prefQ  = p; p += BH_ * NC_ * DH_;
  float* prefK  = p; p += BH_ * NC_ * DH_;
  float* sumQSI = p; p += BH_ * NC_ * DH_;
  float* sumKSO = p; p += BH_ * NC_ * DH_;
  float* prefQSI= p; p += BH_ * NC_ * DH_;
  float* prefKSO= p; p += BH_ * NC_ * DH_;
  float* sumE   = p; p += BH_ * NC_;
  float* prefE  = p; p += BH_ * NC_;

  const dim3 gg(BL_ / 64, D_ / 64);
  gemm_k<true,  true ><<<gg, 256, 0, stream>>>(queries, Wq, bq, Qb);
  gemm_k<true,  true ><<<gg, 256, 0, stream>>>(keys,    Wk, bk, Kb);
  gemm_k<false, true ><<<gg, 256, 0, stream>>>(values,  Wv, bv, Vb);

  flow_chunksum_k<<<BH_ * NC_, 64, 0, stream>>>(Qb, Kb, sumQ, sumK);
  flow_prefix2_k <<<BH_, 64, 0, stream>>>(sumQ, sumK, prefQ, prefK);
  flow_phase1_k  <<<BH_ * NC_, 64, 0, stream>>>(Qb, Kb, prefQ, prefK,
                                                qscale, si_a, so_a, sumQSI, sumKSO);
  flow_prefix2_k <<<BH_, 64, 0, stream>>>(sumQSI, sumKSO, prefQSI, prefKSO);
  flow_phase2_k  <<<BH_ * NC_, 64, 0, stream>>>(Qb, Kb, prefQSI, prefKSO, si_a, so_a,
                                                salloc, e_a, sumE);
  flow_prefixE_k <<<1, 16, 0, stream>>>(sumE, prefE);
  flow_comp_k    <<<BH_ * NC_, 64, 0, stream>>>(e_a, prefE, comp);

  chunk_kv_k<<<BH_ * NC_, 256, 0, stream>>>(Kb, Vb, comp, KVb);
  kv_prefix_k<<<BH_, 256, 0, stream>>>(KVb);
  attn_k<<<BH_ * NC_, 256, 0, stream>>>(Qb, Kb, Vb, KVb, qscale, salloc, comp, Xb);
  gemm_k<false, false><<<gg, 256, 0, stream>>>(Xb, Wo, bo, (float*)d_out);
}

// Round 3
// 149.111 us; speedup vs baseline: 7.4573x; 1.5185x over previous
//
#include <hip/hip_runtime.h>
#include <math.h>

#define EPSF 1e-6f

constexpr int B_  = 2;
constexpr int L_  = 1024;
constexpr int D_  = 512;
constexpr int H_  = 8;
constexpr int DH_ = 64;
constexpr int BL_ = B_ * L_;   // 2048
constexpr int BH_ = B_ * H_;   // 16
constexpr int CT_ = 64;        // chunk length (flow + attention)
constexpr int NC_ = L_ / CT_;  // 16 chunks

typedef __attribute__((ext_vector_type(8))) short bf16x8;
typedef __attribute__((ext_vector_type(4))) float f32x4;

__device__ __forceinline__ unsigned short f2bf(float f) {
  union { float f; unsigned int u; } v; v.f = f;
  const unsigned int u = v.u;
  return (unsigned short)((u + 0x7FFFu + ((u >> 16) & 1u)) >> 16);  // RNE
}

// ---------------------------------------------------------------------------
// MFMA bf16 GEMM: out[M,N] = A[M,512] @ W[512,N] + bias (+sigmoid) (+perm
// store to [B,H,L,Dh]).  Block = 64x64 tile, 256 thr = 4 waves (2x2), each
// wave 32x32 = 2x2 frags of mfma_f32_16x16x32_bf16.  A,W converted fp32->bf16
// in registers during staging.  Depth-1 prefetch (grid = 1 block/CU).
// LDS rows padded to 40 bf16 (80 B) -> full bank spread, 16B-aligned b128.
// ---------------------------------------------------------------------------
template <bool SIG, bool PERM>
__global__ __launch_bounds__(256) void gemm_mfma_k(const float* __restrict__ A,
                                                   const float* __restrict__ W,
                                                   const float* __restrict__ bias,
                                                   float* __restrict__ out) {
  __shared__ __align__(16) short Als[64 * 40];  // [row][k] bf16
  __shared__ __align__(16) short Bls[64 * 40];  // [col][k] bf16
  const int tid = threadIdx.x;
  const int m0 = blockIdx.x * 64, n0 = blockIdx.y * 64;
  // staging roles
  const int arow = tid >> 2, akq = (tid & 3) << 3;  // A: 8 k-contig floats
  const int bcol = tid & 63, bk0 = (tid >> 6) << 3; // B: 8 k-strided floats, 1 col
  // compute roles
  const int lane = tid & 63, wid = tid >> 6;
  const int wr = wid >> 1, wc = wid & 1;
  const int lrow = lane & 15, lk = (lane >> 4) << 3;

  f32x4 acc[2][2] = {{{0.f, 0.f, 0.f, 0.f}, {0.f, 0.f, 0.f, 0.f}},
                     {{0.f, 0.f, 0.f, 0.f}, {0.f, 0.f, 0.f, 0.f}}};
  float ra[8], rb[8];

  auto loadAB = [&](int kt) {
    const float4 f0 = *(const float4*)&A[(size_t)(m0 + arow) * D_ + kt + akq];
    const float4 f1 = *(const float4*)&A[(size_t)(m0 + arow) * D_ + kt + akq + 4];
    ra[0] = f0.x; ra[1] = f0.y; ra[2] = f0.z; ra[3] = f0.w;
    ra[4] = f1.x; ra[5] = f1.y; ra[6] = f1.z; ra[7] = f1.w;
    const float* gw = &W[(size_t)(kt + bk0) * D_ + n0 + bcol];
#pragma unroll
    for (int j = 0; j < 8; ++j) rb[j] = gw[(size_t)j * D_];
  };
  auto writeLDS = [&]() {
    bf16x8 pa, pb;
#pragma unroll
    for (int j = 0; j < 8; ++j) {
      pa[j] = (short)f2bf(ra[j]);
      pb[j] = (short)f2bf(rb[j]);
    }
    *(bf16x8*)&Als[arow * 40 + akq] = pa;
    *(bf16x8*)&Bls[bcol * 40 + bk0] = pb;
  };
  auto compute = [&]() {
    bf16x8 a0 = *(const bf16x8*)&Als[(wr * 32 + lrow) * 40 + lk];
    bf16x8 a1 = *(const bf16x8*)&Als[(wr * 32 + 16 + lrow) * 40 + lk];
    bf16x8 b0 = *(const bf16x8*)&Bls[(wc * 32 + lrow) * 40 + lk];
    bf16x8 b1 = *(const bf16x8*)&Bls[(wc * 32 + 16 + lrow) * 40 + lk];
    acc[0][0] = __builtin_amdgcn_mfma_f32_16x16x32_bf16(a0, b0, acc[0][0], 0, 0, 0);
    acc[0][1] = __builtin_amdgcn_mfma_f32_16x16x32_bf16(a0, b1, acc[0][1], 0, 0, 0);
    acc[1][0] = __builtin_amdgcn_mfma_f32_16x16x32_bf16(a1, b0, acc[1][0], 0, 0, 0);
    acc[1][1] = __builtin_amdgcn_mfma_f32_16x16x32_bf16(a1, b1, acc[1][1], 0, 0, 0);
  };

  loadAB(0);
  writeLDS();
  for (int kt = 32; kt < D_; kt += 32) {
    loadAB(kt);       // prefetch next tile into regs (hides under compute)
    __syncthreads();  // LDS tile ready
    compute();
    __syncthreads();  // all reads done before overwrite
    writeLDS();
  }
  __syncthreads();
  compute();

  // epilogue
#pragma unroll
  for (int j = 0; j < 2; ++j) {
    const int col = n0 + wc * 32 + j * 16 + lrow;
    const float bv = bias[col];
#pragma unroll
    for (int i = 0; i < 2; ++i) {
#pragma unroll
      for (int r = 0; r < 4; ++r) {
        const int row = m0 + wr * 32 + i * 16 + (lane >> 4) * 4 + r;
        float x = acc[i][j][r] + bv;
        if (SIG) x = 1.0f / (1.0f + expf(-x));
        if (PERM) {
          const int b = row >> 10, l = row & (L_ - 1);
          const int h = col >> 6, dh = col & 63;
          out[(((size_t)(b * H_ + h)) * L_ + l) * DH_ + dh] = x;
        } else {
          out[(size_t)row * D_ + col] = x;
        }
      }
    }
  }
}

// ---------------------------------------------------------------------------
// Flow pass, chunk-parallel.  bc = bh*NC + c;  rows g = bc*CT (== bh*L + c*CT).
// ---------------------------------------------------------------------------

// FA: per-chunk column sums of Q and K. grid BH*NC, 64 thr, lane = d.
__global__ __launch_bounds__(64) void flow_chunksum_k(const float* __restrict__ Q,
                                                      const float* __restrict__ K,
                                                      float* __restrict__ sumQ,
                                                      float* __restrict__ sumK) {
  const int bc = blockIdx.x, d = threadIdx.x;
  const float* q = Q + (size_t)bc * CT_ * DH_;
  const float* k = K + (size_t)bc * CT_ * DH_;
  float sq = 0.f, sk = 0.f;
  for (int l = 0; l < CT_; ++l) { sq += q[l * DH_ + d]; sk += k[l * DH_ + d]; }
  sumQ[bc * DH_ + d] = sq;
  sumK[bc * DH_ + d] = sk;
}

// FB: exclusive prefix over chunks (vector of 64 dims). grid BH, 64 thr.
__global__ __launch_bounds__(64) void flow_prefix2_k(const float* __restrict__ sA,
                                                     const float* __restrict__ sB,
                                                     float* __restrict__ pA,
                                                     float* __restrict__ pB) {
  const int bh = blockIdx.x, d = threadIdx.x;
  float ra = 0.f, rb = 0.f;
  for (int c = 0; c < NC_; ++c) {
    const int i = (bh * NC_ + c) * DH_ + d;
    pA[i] = ra; pB[i] = rb;
    ra += sA[i]; rb += sB[i];
  }
}

// FC: phase 1 — a,b via per-d wave scans; outputs qscale, si, so and chunk
// sums of q*si, k*so. grid BH*NC, 64 thr, lane = l.
__global__ __launch_bounds__(64) void flow_phase1_k(const float* __restrict__ Q,
                                                    const float* __restrict__ K,
                                                    const float* __restrict__ prefQ,
                                                    const float* __restrict__ prefK,
                                                    float* __restrict__ qscale,
                                                    float* __restrict__ si_a,
                                                    float* __restrict__ so_a,
                                                    float* __restrict__ sumQSI,
                                                    float* __restrict__ sumKSO) {
  const int bc = blockIdx.x, c = bc & (NC_ - 1);
  const int lane = threadIdx.x;
  const int g = bc * CT_;
  __shared__ float qS[CT_][DH_ + 1];
  __shared__ float kS[CT_][DH_ + 1];
  for (int i = lane; i < CT_ * DH_; i += 64) {
    const int l = i >> 6, d = i & 63;
    qS[l][d] = Q[(size_t)g * DH_ + i];
    kS[l][d] = K[(size_t)g * DH_ + i];
  }
  __syncthreads();
  const int base = bc * DH_;
  float a = 0.f, b = 0.f;
  for (int d = 0; d < DH_; ++d) {
    const float qv = qS[lane][d];
    const float kv = kS[lane][d];
    float ck = kv, cq = qv;
#pragma unroll
    for (int off = 1; off < 64; off <<= 1) {
      const float t1 = __shfl_up(ck, off);
      const float t2 = __shfl_up(cq, off);
      ck += (lane >= off) ? t1 : 0.f;
      cq += (lane >= off) ? t2 : 0.f;
    }
    ck += prefK[base + d];
    cq += prefQ[base + d];
    a += (qv + EPSF) * (ck + EPSF);
    b += (kv + EPSF) * (cq + EPSF);
  }
  const float normal = (float)(c * CT_ + lane + 1);
  const float si = normal / a, so = normal / b;
  qscale[g + lane] = 1.0f / a;
  si_a[g + lane] = si;
  so_a[g + lane] = so;
  float sqsi = 0.f, skso = 0.f;
  for (int l = 0; l < CT_; ++l) {
    const float sil = __shfl(si, l);
    const float sol = __shfl(so, l);
    sqsi += qS[l][lane] * sil;
    skso += kS[l][lane] * sol;
  }
  sumQSI[base + lane] = sqsi;
  sumKSO[base + lane] = skso;
}

// FE: phase 2 — conserved sink/source, salloc, e=exp(clip), chunk sum of e.
__global__ __launch_bounds__(64) void flow_phase2_k(const float* __restrict__ Q,
                                                    const float* __restrict__ K,
                                                    const float* __restrict__ prefQSI,
                                                    const float* __restrict__ prefKSO,
                                                    const float* __restrict__ si_a,
                                                    const float* __restrict__ so_a,
                                                    float* __restrict__ salloc,
                                                    float* __restrict__ e_a,
                                                    float* __restrict__ sumE) {
  const int bc = blockIdx.x, c = bc & (NC_ - 1);
  const int lane = threadIdx.x;
  const int g = bc * CT_;
  __shared__ float qS[CT_][DH_ + 1];
  __shared__ float kS[CT_][DH_ + 1];
  for (int i = lane; i < CT_ * DH_; i += 64) {
    const int l = i >> 6, d = i & 63;
    qS[l][d] = Q[(size_t)g * DH_ + i];
    kS[l][d] = K[(size_t)g * DH_ + i];
  }
  __syncthreads();
  const float si = si_a[g + lane];
  const float so = so_a[g + lane];
  const int base = bc * DH_;
  float c1 = 0.f, c2 = 0.f;
  for (int d = 0; d < DH_; ++d) {
    const float qv = qS[lane][d];
    const float kv = kS[lane][d];
    float ckso = kv * so, cqsi = qv * si;
#pragma unroll
    for (int off = 1; off < 64; off <<= 1) {
      const float t1 = __shfl_up(ckso, off);
      const float t2 = __shfl_up(cqsi, off);
      ckso += (lane >= off) ? t1 : 0.f;
      cqsi += (lane >= off) ? t2 : 0.f;
    }
    ckso += prefKSO[base + d];
    cqsi += prefQSI[base + d];
    c1 += (qv + EPSF) * (ckso + EPSF);
    c2 += (kv + EPSF) * (cqsi + EPSF);
  }
  const float normal = (float)(c * CT_ + lane + 1);
  const float cs_sink = c1 / normal;
  salloc[g + lane] = 1.0f / (1.0f + expf(-cs_sink));
  float cs_src = c2 / normal;
  cs_src = fminf(1.0f, fmaxf(-1.0f, cs_src));
  const float e = expf(cs_src);
  e_a[g + lane] = e;
  float tot = e;
#pragma unroll
  for (int off = 32; off; off >>= 1) tot += __shfl_xor(tot, off);
  if (lane == 0) sumE[bc] = tot;
}

// FF: scalar exclusive prefix of chunk e-sums. grid 1, 16 thr (t = bh).
__global__ void flow_prefixE_k(const float* __restrict__ sumE, float* __restrict__ prefE) {
  const int bh = threadIdx.x;
  if (bh >= BH_) return;
  float r = 0.f;
  for (int c = 0; c < NC_; ++c) {
    prefE[bh * NC_ + c] = r;
    r += sumE[bh * NC_ + c];
  }
}

// FG: source_competition. grid BH*NC, 64 thr, lane = l.
__global__ __launch_bounds__(64) void flow_comp_k(const float* __restrict__ e_a,
                                                  const float* __restrict__ prefE,
                                                  float* __restrict__ comp) {
  const int bc = blockIdx.x, c = bc & (NC_ - 1);
  const int lane = threadIdx.x;
  const int g = bc * CT_;
  const float e = e_a[g + lane];
  float s = e;
#pragma unroll
  for (int off = 1; off < 64; off <<= 1) {
    const float t = __shfl_up(s, off);
    s += (lane >= off) ? t : 0.f;
  }
  const float cume = prefE[bc] + s;
  comp[g + lane] = e / cume * (float)(c * CT_ + lane + 1);
}

// ---------------------------------------------------------------------------
// Chunk-local KV sums: KV[bc][d][m] = sum_{l in chunk} k[l,d] * (v[l,m]*comp[l])
// ---------------------------------------------------------------------------
__global__ __launch_bounds__(256) void chunk_kv_k(const float* __restrict__ K,
                                                  const float* __restrict__ V,
                                                  const float* __restrict__ comp,
                                                  float* __restrict__ KV) {
  const int bc = blockIdx.x;
  const int g = bc * CT_;
  const float* k = K + (size_t)g * DH_;
  const float* v = V + (size_t)g * DH_;
  __shared__ float kb[CT_][DH_];
  __shared__ float vb[CT_][DH_];
  const int tid = threadIdx.x;
  for (int i = tid; i < CT_ * DH_; i += 256) {
    const int l = i >> 6;
    kb[l][i & 63] = k[i];
    vb[l][i & 63] = v[i] * comp[g + l];
  }
  __syncthreads();
  const int m = tid & 63, dg = tid >> 6;
  float acc[16] = {};
  for (int l = 0; l < CT_; ++l) {
    const float vm = vb[l][m];
#pragma unroll
    for (int i = 0; i < 16; ++i) acc[i] += kb[l][dg * 16 + i] * vm;
  }
  float* out = KV + ((size_t)bc * DH_ + dg * 16) * DH_ + m;
#pragma unroll
  for (int i = 0; i < 16; ++i) out[i * DH_] = acc[i];
}

// In-place exclusive prefix over chunks of KV. grid BH, 256 thr.
__global__ __launch_bounds__(256) void kv_prefix_k(float* __restrict__ KV) {
  const int bh = blockIdx.x;
  const int tid = threadIdx.x;
  for (int p = tid; p < DH_ * DH_; p += 256) {
    float run = 0.f;
    const size_t base = (size_t)bh * NC_ * DH_ * DH_ + p;
#pragma unroll
    for (int c = 0; c < NC_; ++c) {
      const float t = KV[base + (size_t)c * DH_ * DH_];
      KV[base + (size_t)c * DH_ * DH_] = run;
      run += t;
    }
  }
}

// Per-chunk attention: out = (qp @ KVprefix + tril(qp k^T) v') * salloc
__global__ __launch_bounds__(256) void attn_k(const float* __restrict__ Q,
                                              const float* __restrict__ K,
                                              const float* __restrict__ V,
                                              const float* __restrict__ KV,
                                              const float* __restrict__ qscale,
                                              const float* __restrict__ salloc,
                                              const float* __restrict__ comp,
                                              float* __restrict__ X) {
  const int bc = blockIdx.x;
  const int bh = bc >> 4, c = bc & (NC_ - 1);
  const int bb = bh >> 3, hh = bh & (H_ - 1);
  const int g = bc * CT_;
  __shared__ float qp[CT_][DH_ + 4];
  __shared__ float kb[CT_][DH_];
  __shared__ float S[CT_][CT_ + 4];
  const int tid = threadIdx.x;
  for (int i = tid; i < CT_ * DH_; i += 256) {
    const int l = i >> 6, d = i & 63;
    qp[l][d] = Q[(size_t)g * DH_ + i] * qscale[g + l];
    kb[l][d] = K[(size_t)g * DH_ + i];
  }
  __syncthreads();
  const int m = tid & 63, w = tid >> 6;
  float acc[16] = {};
  const float* kvp = KV + (size_t)bc * DH_ * DH_;
  for (int d4 = 0; d4 < 16; ++d4) {
    float kvv[4];
#pragma unroll
    for (int e = 0; e < 4; ++e) kvv[e] = kvp[(d4 * 4 + e) * DH_ + m];
#pragma unroll
    for (int i = 0; i < 16; ++i) {
      const float4 q4 = *(const float4*)&qp[w * 16 + i][d4 * 4];
      acc[i] += q4.x * kvv[0] + q4.y * kvv[1] + q4.z * kvv[2] + q4.w * kvv[3];
    }
  }
  {
    float sc[16] = {};
    for (int d4 = 0; d4 < 16; ++d4) {
      const float4 q4 = *(const float4*)&qp[m][d4 * 4];
#pragma unroll
      for (int i = 0; i < 16; ++i) {
        const float4 k4 = *(const float4*)&kb[w * 16 + i][d4 * 4];
        sc[i] += q4.x * k4.x + q4.y * k4.y + q4.z * k4.z + q4.w * k4.w;
      }
    }
#pragma unroll
    for (int i = 0; i < 16; ++i) {
      const int j = w * 16 + i;
      S[m][j] = (j <= m) ? sc[i] : 0.0f;
    }
  }
  __syncthreads();
  for (int j4 = 0; j4 < 16; ++j4) {
    float vv[4];
#pragma unroll
    for (int e = 0; e < 4; ++e) {
      const int j = j4 * 4 + e;
      vv[e] = V[(size_t)(g + j) * DH_ + m] * comp[g + j];
    }
#pragma unroll
    for (int i = 0; i < 16; ++i) {
      const float4 s4 = *(const float4*)&S[w * 16 + i][j4 * 4];
      acc[i] += s4.x * vv[0] + s4.y * vv[1] + s4.z * vv[2] + s4.w * vv[3];
    }
  }
#pragma unroll
  for (int i = 0; i < 16; ++i) {
    const int l = w * 16 + i;
    X[((size_t)(bb * L_ + c * CT_ + l)) * D_ + hh * DH_ + m] = acc[i] * salloc[g + l];
  }
}

// ---------------------------------------------------------------------------
extern "C" void kernel_launch(void* const* d_in, const int* in_sizes, int n_in,
                              void* d_out, int out_size, void* d_ws, size_t ws_size,
                              hipStream_t stream) {
  (void)in_sizes; (void)n_in; (void)out_size; (void)ws_size;
  const float* queries = (const float*)d_in[0];
  const float* keys    = (const float*)d_in[1];
  const float* values  = (const float*)d_in[2];
  const float* Wq = (const float*)d_in[3];
  const float* bq = (const float*)d_in[4];
  const float* Wk = (const float*)d_in[5];
  const float* bk = (const float*)d_in[6];
  const float* Wv = (const float*)d_in[7];
  const float* bv = (const float*)d_in[8];
  const float* Wo = (const float*)d_in[9];
  const float* bo = (const float*)d_in[10];

  float* ws = (float*)d_ws;
  const size_t seg = (size_t)BH_ * L_ * DH_;  // 1,048,576 floats
  float* Qb  = ws;
  float* Kb  = Qb + seg;
  float* Vb  = Kb + seg;
  float* Xb  = Vb + seg;                       // [BL, D]
  float* KVb = Xb + (size_t)BL_ * D_;          // [BH, NC, DH, DH]
  float* p   = KVb + (size_t)BH_ * NC_ * DH_ * DH_;
  float* qscale = p; p += BH_ * L_;
  float* salloc = p; p += BH_ * L_;
  float* comp   = p; p += BH_ * L_;
  float* si_a   = p; p += BH_ * L_;
  float* so_a   = p; p += BH_ * L_;
  float* e_a    = p; p += BH_ * L_;
  float* sumQ   = p; p += BH_ * NC_ * DH_;
  float* sumK   = p; p += BH_ * NC_ * DH_;
  float* prefQ  = p; p += BH_ * NC_ * DH_;
  float* prefK  = p; p += BH_ * NC_ * DH_;
  float* sumQSI = p; p += BH_ * NC_ * DH_;
  float* sumKSO = p; p += BH_ * NC_ * DH_;
  float* prefQSI= p; p += BH_ * NC_ * DH_;
  float* prefKSO= p; p += BH_ * NC_ * DH_;
  float* sumE   = p; p += BH_ * NC_;
  float* prefE  = p; p += BH_ * NC_;

  const dim3 gg(BL_ / 64, D_ / 64);
  gemm_mfma_k<true,  true ><<<gg, 256, 0, stream>>>(queries, Wq, bq, Qb);
  gemm_mfma_k<true,  true ><<<gg, 256, 0, stream>>>(keys,    Wk, bk, Kb);
  gemm_mfma_k<false, true ><<<gg, 256, 0, stream>>>(values,  Wv, bv, Vb);

  flow_chunksum_k<<<BH_ * NC_, 64, 0, stream>>>(Qb, Kb, sumQ, sumK);
  flow_prefix2_k <<<BH_, 64, 0, stream>>>(sumQ, sumK, prefQ, prefK);
  flow_phase1_k  <<<BH_ * NC_, 64, 0, stream>>>(Qb, Kb, prefQ, prefK,
                                                qscale, si_a, so_a, sumQSI, sumKSO);
  flow_prefix2_k <<<BH_, 64, 0, stream>>>(sumQSI, sumKSO, prefQSI, prefKSO);
  flow_phase2_k  <<<BH_ * NC_, 64, 0, stream>>>(Qb, Kb, prefQSI, prefKSO, si_a, so_a,
                                                salloc, e_a, sumE);
  flow_prefixE_k <<<1, 16, 0, stream>>>(sumE, prefE);
  flow_comp_k    <<<BH_ * NC_, 64, 0, stream>>>(e_a, prefE, comp);

  chunk_kv_k<<<BH_ * NC_, 256, 0, stream>>>(Kb, Vb, comp, KVb);
  kv_prefix_k<<<BH_, 256, 0, stream>>>(KVb);
  attn_k<<<BH_ * NC_, 256, 0, stream>>>(Qb, Kb, Vb, KVb, qscale, salloc, comp, Xb);
  gemm_mfma_k<false, false><<<gg, 256, 0, stream>>>(Xb, Wo, bo, (float*)d_out);
}

// Round 4
// 128.728 us; speedup vs baseline: 8.6381x; 1.1583x over previous
//
#include <hip/hip_runtime.h>
#include <math.h>

#define EPSF 1e-6f

constexpr int B_  = 2;
constexpr int L_  = 1024;
constexpr int D_  = 512;
constexpr int H_  = 8;
constexpr int DH_ = 64;
constexpr int BL_ = B_ * L_;   // 2048
constexpr int BH_ = B_ * H_;   // 16
constexpr int CT_ = 64;        // chunk length (flow + attention)
constexpr int NC_ = L_ / CT_;  // 16 chunks

typedef __attribute__((ext_vector_type(8))) short bf16x8;
typedef __attribute__((ext_vector_type(4))) float f32x4;

__device__ __forceinline__ unsigned short f2bf(float f) {
  union { float f; unsigned int u; } v; v.f = f;
  const unsigned int u = v.u;
  return (unsigned short)((u + 0x7FFFu + ((u >> 16) & 1u)) >> 16);  // RNE
}

// ---------------------------------------------------------------------------
// Fused projection GEMMs (z = 0:Q, 1:K, 2:V): out = sigmoid?(A @ W + b),
// permuted store to [B,H,L,Dh]. For z<2 additionally writes per-(chunk,head)
// column sums (the flow pass's FA stage) — each 64x64 tile IS one chunk.
// Block = 64x64 tile, 256 thr = 4 waves (2x2), wave = 32x32 via 2x2
// mfma_f32_16x16x32_bf16. Depth-1 register prefetch.
// ---------------------------------------------------------------------------
__global__ __launch_bounds__(256) void proj3_k(const float* __restrict__ Qin,
                                               const float* __restrict__ Kin,
                                               const float* __restrict__ Vin,
                                               const float* __restrict__ Wq,
                                               const float* __restrict__ bq,
                                               const float* __restrict__ Wk,
                                               const float* __restrict__ bk,
                                               const float* __restrict__ Wv,
                                               const float* __restrict__ bv,
                                               float* __restrict__ Qb,
                                               float* __restrict__ Kb,
                                               float* __restrict__ Vb,
                                               float* __restrict__ sumQ,
                                               float* __restrict__ sumK) {
  const int z = blockIdx.z;
  const float* A    = (z == 0) ? Qin : (z == 1) ? Kin : Vin;
  const float* W    = (z == 0) ? Wq  : (z == 1) ? Wk  : Wv;
  const float* bias = (z == 0) ? bq  : (z == 1) ? bk  : bv;
  float* out        = (z == 0) ? Qb  : (z == 1) ? Kb  : Vb;
  float* csum       = (z == 0) ? sumQ : (z == 1) ? sumK : nullptr;
  const bool sig = (z < 2);

  __shared__ __align__(16) short Als[64 * 40];  // [row][k] bf16, pad->40
  __shared__ __align__(16) short Bls[64 * 40];  // [col][k] bf16
  const int tid = threadIdx.x;
  const int m0 = blockIdx.x * 64, n0 = blockIdx.y * 64;
  const int arow = tid >> 2, akq = (tid & 3) << 3;
  const int bcol = tid & 63, bk0 = (tid >> 6) << 3;
  const int lane = tid & 63, wid = tid >> 6;
  const int wr = wid >> 1, wc = wid & 1;
  const int lrow = lane & 15, lk = (lane >> 4) << 3;

  f32x4 acc[2][2] = {{{0.f, 0.f, 0.f, 0.f}, {0.f, 0.f, 0.f, 0.f}},
                     {{0.f, 0.f, 0.f, 0.f}, {0.f, 0.f, 0.f, 0.f}}};
  float ra[8], rb[8];

  auto loadAB = [&](int kt) {
    const float4 f0 = *(const float4*)&A[(size_t)(m0 + arow) * D_ + kt + akq];
    const float4 f1 = *(const float4*)&A[(size_t)(m0 + arow) * D_ + kt + akq + 4];
    ra[0] = f0.x; ra[1] = f0.y; ra[2] = f0.z; ra[3] = f0.w;
    ra[4] = f1.x; ra[5] = f1.y; ra[6] = f1.z; ra[7] = f1.w;
    const float* gw = &W[(size_t)(kt + bk0) * D_ + n0 + bcol];
#pragma unroll
    for (int j = 0; j < 8; ++j) rb[j] = gw[(size_t)j * D_];
  };
  auto writeLDS = [&]() {
    bf16x8 pa, pb;
#pragma unroll
    for (int j = 0; j < 8; ++j) {
      pa[j] = (short)f2bf(ra[j]);
      pb[j] = (short)f2bf(rb[j]);
    }
    *(bf16x8*)&Als[arow * 40 + akq] = pa;
    *(bf16x8*)&Bls[bcol * 40 + bk0] = pb;
  };
  auto compute = [&]() {
    bf16x8 a0 = *(const bf16x8*)&Als[(wr * 32 + lrow) * 40 + lk];
    bf16x8 a1 = *(const bf16x8*)&Als[(wr * 32 + 16 + lrow) * 40 + lk];
    bf16x8 b0 = *(const bf16x8*)&Bls[(wc * 32 + lrow) * 40 + lk];
    bf16x8 b1 = *(const bf16x8*)&Bls[(wc * 32 + 16 + lrow) * 40 + lk];
    acc[0][0] = __builtin_amdgcn_mfma_f32_16x16x32_bf16(a0, b0, acc[0][0], 0, 0, 0);
    acc[0][1] = __builtin_amdgcn_mfma_f32_16x16x32_bf16(a0, b1, acc[0][1], 0, 0, 0);
    acc[1][0] = __builtin_amdgcn_mfma_f32_16x16x32_bf16(a1, b0, acc[1][0], 0, 0, 0);
    acc[1][1] = __builtin_amdgcn_mfma_f32_16x16x32_bf16(a1, b1, acc[1][1], 0, 0, 0);
  };

  loadAB(0);
  writeLDS();
  for (int kt = 32; kt < D_; kt += 32) {
    loadAB(kt);
    __syncthreads();
    compute();
    __syncthreads();
    writeLDS();
  }
  __syncthreads();
  compute();

  // epilogue: bias (+sigmoid), permuted store, per-column partial sums
  const int b = m0 >> 10, h = n0 >> 6;
  float psum[2] = {0.f, 0.f};
#pragma unroll
  for (int j = 0; j < 2; ++j) {
    const int col = n0 + wc * 32 + j * 16 + lrow;
    const float bv4 = bias[col];
    const int dh = col & 63;
#pragma unroll
    for (int i = 0; i < 2; ++i) {
#pragma unroll
      for (int r = 0; r < 4; ++r) {
        const int row = m0 + wr * 32 + i * 16 + (lane >> 4) * 4 + r;
        float x = acc[i][j][r] + bv4;
        if (sig) x = 1.0f / (1.0f + expf(-x));
        const int l = row & (L_ - 1);
        out[(((size_t)(b * H_ + h)) * L_ + l) * DH_ + dh] = x;
        psum[j] += x;
      }
    }
  }
  if (csum) {
    // reduce across the 4 row-groups (lane>>4) -> column sum for this wr half
    float* sumS = (float*)Als;  // reuse LDS: [2][64]
#pragma unroll
    for (int j = 0; j < 2; ++j) {
      psum[j] += __shfl_xor(psum[j], 16);
      psum[j] += __shfl_xor(psum[j], 32);
      if ((lane >> 4) == 0) sumS[wr * 64 + wc * 32 + j * 16 + lrow] = psum[j];
    }
    __syncthreads();
    if (tid < 64) {
      const int c = (m0 & (L_ - 1)) >> 6;
      const int bc = (b * H_ + h) * NC_ + c;
      csum[bc * DH_ + tid] = sumS[tid] + sumS[64 + tid];
    }
  }
}

// ---------------------------------------------------------------------------
// Flow phase 1: a,b via per-d wave scans (inline chunk-prefix from sumQ/sumK);
// outputs qscale, si, so and chunk sums of q*si, k*so. grid BH*NC, 64 thr.
// ---------------------------------------------------------------------------
__global__ __launch_bounds__(64) void flow_phase1_k(const float* __restrict__ Q,
                                                    const float* __restrict__ K,
                                                    const float* __restrict__ sumQ,
                                                    const float* __restrict__ sumK,
                                                    float* __restrict__ qscale,
                                                    float* __restrict__ si_a,
                                                    float* __restrict__ so_a,
                                                    float* __restrict__ sumQSI,
                                                    float* __restrict__ sumKSO) {
  const int bc = blockIdx.x, bh = bc >> 4, c = bc & (NC_ - 1);
  const int lane = threadIdx.x;
  const int g = bc * CT_;
  __shared__ float qS[CT_][DH_ + 1];
  __shared__ float kS[CT_][DH_ + 1];
  __shared__ float pqS[DH_], pkS[DH_];
  for (int i = lane; i < CT_ * DH_; i += 64) {
    const int l = i >> 6, d = i & 63;
    qS[l][d] = Q[(size_t)g * DH_ + i];
    kS[l][d] = K[(size_t)g * DH_ + i];
  }
  {  // inline exclusive chunk prefix (lane = d)
    float pq = 0.f, pk = 0.f;
    for (int cc = 0; cc < c; ++cc) {
      pq += sumQ[(bh * NC_ + cc) * DH_ + lane];
      pk += sumK[(bh * NC_ + cc) * DH_ + lane];
    }
    pqS[lane] = pq; pkS[lane] = pk;
  }
  __syncthreads();
  float a = 0.f, b = 0.f;
  for (int d = 0; d < DH_; ++d) {
    const float qv = qS[lane][d];
    const float kv = kS[lane][d];
    float ck = kv, cq = qv;
#pragma unroll
    for (int off = 1; off < 64; off <<= 1) {
      const float t1 = __shfl_up(ck, off);
      const float t2 = __shfl_up(cq, off);
      ck += (lane >= off) ? t1 : 0.f;
      cq += (lane >= off) ? t2 : 0.f;
    }
    ck += pkS[d];
    cq += pqS[d];
    a += (qv + EPSF) * (ck + EPSF);
    b += (kv + EPSF) * (cq + EPSF);
  }
  const float normal = (float)(c * CT_ + lane + 1);
  const float si = normal / a, so = normal / b;
  qscale[g + lane] = 1.0f / a;
  si_a[g + lane] = si;
  so_a[g + lane] = so;
  float sqsi = 0.f, skso = 0.f;
  for (int l = 0; l < CT_; ++l) {
    const float sil = __shfl(si, l);
    const float sol = __shfl(so, l);
    sqsi += qS[l][lane] * sil;
    skso += kS[l][lane] * sol;
  }
  sumQSI[bc * DH_ + lane] = sqsi;
  sumKSO[bc * DH_ + lane] = skso;
}

// ---------------------------------------------------------------------------
// Flow phase 2: conserved sink/source (inline prefix), salloc, e, chunk sumE.
// ---------------------------------------------------------------------------
__global__ __launch_bounds__(64) void flow_phase2_k(const float* __restrict__ Q,
                                                    const float* __restrict__ K,
                                                    const float* __restrict__ sumQSI,
                                                    const float* __restrict__ sumKSO,
                                                    const float* __restrict__ si_a,
                                                    const float* __restrict__ so_a,
                                                    float* __restrict__ salloc,
                                                    float* __restrict__ e_a,
                                                    float* __restrict__ sumE) {
  const int bc = blockIdx.x, bh = bc >> 4, c = bc & (NC_ - 1);
  const int lane = threadIdx.x;
  const int g = bc * CT_;
  __shared__ float qS[CT_][DH_ + 1];
  __shared__ float kS[CT_][DH_ + 1];
  __shared__ float pqS[DH_], pkS[DH_];
  for (int i = lane; i < CT_ * DH_; i += 64) {
    const int l = i >> 6, d = i & 63;
    qS[l][d] = Q[(size_t)g * DH_ + i];
    kS[l][d] = K[(size_t)g * DH_ + i];
  }
  {
    float pq = 0.f, pk = 0.f;
    for (int cc = 0; cc < c; ++cc) {
      pq += sumQSI[(bh * NC_ + cc) * DH_ + lane];
      pk += sumKSO[(bh * NC_ + cc) * DH_ + lane];
    }
    pqS[lane] = pq; pkS[lane] = pk;
  }
  __syncthreads();
  const float si = si_a[g + lane];
  const float so = so_a[g + lane];
  float c1 = 0.f, c2 = 0.f;
  for (int d = 0; d < DH_; ++d) {
    const float qv = qS[lane][d];
    const float kv = kS[lane][d];
    float ckso = kv * so, cqsi = qv * si;
#pragma unroll
    for (int off = 1; off < 64; off <<= 1) {
      const float t1 = __shfl_up(ckso, off);
      const float t2 = __shfl_up(cqsi, off);
      ckso += (lane >= off) ? t1 : 0.f;
      cqsi += (lane >= off) ? t2 : 0.f;
    }
    ckso += pkS[d];
    cqsi += pqS[d];
    c1 += (qv + EPSF) * (ckso + EPSF);
    c2 += (kv + EPSF) * (cqsi + EPSF);
  }
  const float normal = (float)(c * CT_ + lane + 1);
  const float cs_sink = c1 / normal;
  salloc[g + lane] = 1.0f / (1.0f + expf(-cs_sink));
  float cs_src = c2 / normal;
  cs_src = fminf(1.0f, fmaxf(-1.0f, cs_src));
  const float e = expf(cs_src);
  e_a[g + lane] = e;
  float tot = e;
#pragma unroll
  for (int off = 32; off; off >>= 1) tot += __shfl_xor(tot, off);
  if (lane == 0) sumE[bc] = tot;
}

// ---------------------------------------------------------------------------
// Fused: source_competition (inline prefix of sumE) + chunk-local KV sums.
// grid BH*NC, 256 thr. Wave 0 computes comp; all waves then build KV.
// ---------------------------------------------------------------------------
__global__ __launch_bounds__(256) void flow_ckv_k(const float* __restrict__ K,
                                                  const float* __restrict__ V,
                                                  const float* __restrict__ e_a,
                                                  const float* __restrict__ sumE,
                                                  float* __restrict__ comp,
                                                  float* __restrict__ KV) {
  const int bc = blockIdx.x, bh = bc >> 4, c = bc & (NC_ - 1);
  const int g = bc * CT_;
  const int tid = threadIdx.x;
  __shared__ float compS[CT_];
  __shared__ float kb[CT_][DH_];
  __shared__ float vb[CT_][DH_];
  if (tid < 64) {
    const int lane = tid;
    const float e = e_a[g + lane];
    float se = (lane < c) ? sumE[bh * NC_ + lane] : 0.f;
#pragma unroll
    for (int off = 32; off; off >>= 1) se += __shfl_xor(se, off);
    float s = e;
#pragma unroll
    for (int off = 1; off < 64; off <<= 1) {
      const float t = __shfl_up(s, off);
      s += (lane >= off) ? t : 0.f;
    }
    const float cf = e / (se + s) * (float)(c * CT_ + lane + 1);
    compS[lane] = cf;
    comp[g + lane] = cf;
  }
  __syncthreads();
  const float* k = K + (size_t)g * DH_;
  const float* v = V + (size_t)g * DH_;
  for (int i = tid; i < CT_ * DH_; i += 256) {
    const int l = i >> 6;
    kb[l][i & 63] = k[i];
    vb[l][i & 63] = v[i] * compS[l];
  }
  __syncthreads();
  const int m = tid & 63, dg = tid >> 6;
  float acc[16] = {};
  for (int l = 0; l < CT_; ++l) {
    const float vm = vb[l][m];
#pragma unroll
    for (int i = 0; i < 16; ++i) acc[i] += kb[l][dg * 16 + i] * vm;
  }
  float* out = KV + ((size_t)bc * DH_ + dg * 16) * DH_ + m;
#pragma unroll
  for (int i = 0; i < 16; ++i) out[i * DH_] = acc[i];
}

// In-place exclusive prefix over chunks of KV. grid BH, 256 thr.
__global__ __launch_bounds__(256) void kv_prefix_k(float* __restrict__ KV) {
  const int bh = blockIdx.x;
  const int tid = threadIdx.x;
  for (int p = tid; p < DH_ * DH_; p += 256) {
    float run = 0.f;
    const size_t base = (size_t)bh * NC_ * DH_ * DH_ + p;
#pragma unroll
    for (int c = 0; c < NC_; ++c) {
      const float t = KV[base + (size_t)c * DH_ * DH_];
      KV[base + (size_t)c * DH_ * DH_] = run;
      run += t;
    }
  }
}

// Per-chunk attention: out = (qp @ KVprefix + tril(qp k^T) v') * salloc
__global__ __launch_bounds__(256) void attn_k(const float* __restrict__ Q,
                                              const float* __restrict__ K,
                                              const float* __restrict__ V,
                                              const float* __restrict__ KV,
                                              const float* __restrict__ qscale,
                                              const float* __restrict__ salloc,
                                              const float* __restrict__ comp,
                                              float* __restrict__ X) {
  const int bc = blockIdx.x;
  const int bh = bc >> 4, c = bc & (NC_ - 1);
  const int bb = bh >> 3, hh = bh & (H_ - 1);
  const int g = bc * CT_;
  __shared__ float qp[CT_][DH_ + 4];
  __shared__ float kb[CT_][DH_];
  __shared__ float S[CT_][CT_ + 4];
  const int tid = threadIdx.x;
  for (int i = tid; i < CT_ * DH_; i += 256) {
    const int l = i >> 6, d = i & 63;
    qp[l][d] = Q[(size_t)g * DH_ + i] * qscale[g + l];
    kb[l][d] = K[(size_t)g * DH_ + i];
  }
  __syncthreads();
  const int m = tid & 63, w = tid >> 6;
  float acc[16] = {};
  const float* kvp = KV + (size_t)bc * DH_ * DH_;
  for (int d4 = 0; d4 < 16; ++d4) {
    float kvv[4];
#pragma unroll
    for (int e = 0; e < 4; ++e) kvv[e] = kvp[(d4 * 4 + e) * DH_ + m];
#pragma unroll
    for (int i = 0; i < 16; ++i) {
      const float4 q4 = *(const float4*)&qp[w * 16 + i][d4 * 4];
      acc[i] += q4.x * kvv[0] + q4.y * kvv[1] + q4.z * kvv[2] + q4.w * kvv[3];
    }
  }
  {
    float sc[16] = {};
    for (int d4 = 0; d4 < 16; ++d4) {
      const float4 q4 = *(const float4*)&qp[m][d4 * 4];
#pragma unroll
      for (int i = 0; i < 16; ++i) {
        const float4 k4 = *(const float4*)&kb[w * 16 + i][d4 * 4];
        sc[i] += q4.x * k4.x + q4.y * k4.y + q4.z * k4.z + q4.w * k4.w;
      }
    }
#pragma unroll
    for (int i = 0; i < 16; ++i) {
      const int j = w * 16 + i;
      S[m][j] = (j <= m) ? sc[i] : 0.0f;
    }
  }
  __syncthreads();
  for (int j4 = 0; j4 < 16; ++j4) {
    float vv[4];
#pragma unroll
    for (int e = 0; e < 4; ++e) {
      const int j = j4 * 4 + e;
      vv[e] = V[(size_t)(g + j) * DH_ + m] * comp[g + j];
    }
#pragma unroll
    for (int i = 0; i < 16; ++i) {
      const float4 s4 = *(const float4*)&S[w * 16 + i][j4 * 4];
      acc[i] += s4.x * vv[0] + s4.y * vv[1] + s4.z * vv[2] + s4.w * vv[3];
    }
  }
#pragma unroll
  for (int i = 0; i < 16; ++i) {
    const int l = w * 16 + i;
    X[((size_t)(bb * L_ + c * CT_ + l)) * D_ + hh * DH_ + m] = acc[i] * salloc[g + l];
  }
}

// ---------------------------------------------------------------------------
// Output GEMM: d_out = X @ Wo + bo (no sigmoid, no perm).
// ---------------------------------------------------------------------------
__global__ __launch_bounds__(256) void gemm_out_k(const float* __restrict__ A,
                                                  const float* __restrict__ W,
                                                  const float* __restrict__ bias,
                                                  float* __restrict__ out) {
  __shared__ __align__(16) short Als[64 * 40];
  __shared__ __align__(16) short Bls[64 * 40];
  const int tid = threadIdx.x;
  const int m0 = blockIdx.x * 64, n0 = blockIdx.y * 64;
  const int arow = tid >> 2, akq = (tid & 3) << 3;
  const int bcol = tid & 63, bk0 = (tid >> 6) << 3;
  const int lane = tid & 63, wid = tid >> 6;
  const int wr = wid >> 1, wc = wid & 1;
  const int lrow = lane & 15, lk = (lane >> 4) << 3;

  f32x4 acc[2][2] = {{{0.f, 0.f, 0.f, 0.f}, {0.f, 0.f, 0.f, 0.f}},
                     {{0.f, 0.f, 0.f, 0.f}, {0.f, 0.f, 0.f, 0.f}}};
  float ra[8], rb[8];
  auto loadAB = [&](int kt) {
    const float4 f0 = *(const float4*)&A[(size_t)(m0 + arow) * D_ + kt + akq];
    const float4 f1 = *(const float4*)&A[(size_t)(m0 + arow) * D_ + kt + akq + 4];
    ra[0] = f0.x; ra[1] = f0.y; ra[2] = f0.z; ra[3] = f0.w;
    ra[4] = f1.x; ra[5] = f1.y; ra[6] = f1.z; ra[7] = f1.w;
    const float* gw = &W[(size_t)(kt + bk0) * D_ + n0 + bcol];
#pragma unroll
    for (int j = 0; j < 8; ++j) rb[j] = gw[(size_t)j * D_];
  };
  auto writeLDS = [&]() {
    bf16x8 pa, pb;
#pragma unroll
    for (int j = 0; j < 8; ++j) {
      pa[j] = (short)f2bf(ra[j]);
      pb[j] = (short)f2bf(rb[j]);
    }
    *(bf16x8*)&Als[arow * 40 + akq] = pa;
    *(bf16x8*)&Bls[bcol * 40 + bk0] = pb;
  };
  auto compute = [&]() {
    bf16x8 a0 = *(const bf16x8*)&Als[(wr * 32 + lrow) * 40 + lk];
    bf16x8 a1 = *(const bf16x8*)&Als[(wr * 32 + 16 + lrow) * 40 + lk];
    bf16x8 b0 = *(const bf16x8*)&Bls[(wc * 32 + lrow) * 40 + lk];
    bf16x8 b1 = *(const bf16x8*)&Bls[(wc * 32 + 16 + lrow) * 40 + lk];
    acc[0][0] = __builtin_amdgcn_mfma_f32_16x16x32_bf16(a0, b0, acc[0][0], 0, 0, 0);
    acc[0][1] = __builtin_amdgcn_mfma_f32_16x16x32_bf16(a0, b1, acc[0][1], 0, 0, 0);
    acc[1][0] = __builtin_amdgcn_mfma_f32_16x16x32_bf16(a1, b0, acc[1][0], 0, 0, 0);
    acc[1][1] = __builtin_amdgcn_mfma_f32_16x16x32_bf16(a1, b1, acc[1][1], 0, 0, 0);
  };

  loadAB(0);
  writeLDS();
  for (int kt = 32; kt < D_; kt += 32) {
    loadAB(kt);
    __syncthreads();
    compute();
    __syncthreads();
    writeLDS();
  }
  __syncthreads();
  compute();

#pragma unroll
  for (int j = 0; j < 2; ++j) {
    const int col = n0 + wc * 32 + j * 16 + lrow;
    const float bv4 = bias[col];
#pragma unroll
    for (int i = 0; i < 2; ++i) {
#pragma unroll
      for (int r = 0; r < 4; ++r) {
        const int row = m0 + wr * 32 + i * 16 + (lane >> 4) * 4 + r;
        out[(size_t)row * D_ + col] = acc[i][j][r] + bv4;
      }
    }
  }
}

// ---------------------------------------------------------------------------
extern "C" void kernel_launch(void* const* d_in, const int* in_sizes, int n_in,
                              void* d_out, int out_size, void* d_ws, size_t ws_size,
                              hipStream_t stream) {
  (void)in_sizes; (void)n_in; (void)out_size; (void)ws_size;
  const float* queries = (const float*)d_in[0];
  const float* keys    = (const float*)d_in[1];
  const float* values  = (const float*)d_in[2];
  const float* Wq = (const float*)d_in[3];
  const float* bq = (const float*)d_in[4];
  const float* Wk = (const float*)d_in[5];
  const float* bk = (const float*)d_in[6];
  const float* Wv = (const float*)d_in[7];
  const float* bv = (const float*)d_in[8];
  const float* Wo = (const float*)d_in[9];
  const float* bo = (const float*)d_in[10];

  float* ws = (float*)d_ws;
  const size_t seg = (size_t)BH_ * L_ * DH_;  // 1,048,576 floats
  float* Qb  = ws;
  float* Kb  = Qb + seg;
  float* Vb  = Kb + seg;
  float* Xb  = Vb + seg;                       // [BL, D]
  float* KVb = Xb + (size_t)BL_ * D_;          // [BH, NC, DH, DH]
  float* p   = KVb + (size_t)BH_ * NC_ * DH_ * DH_;
  float* qscale = p; p += BH_ * L_;
  float* salloc = p; p += BH_ * L_;
  float* comp   = p; p += BH_ * L_;
  float* si_a   = p; p += BH_ * L_;
  float* so_a   = p; p += BH_ * L_;
  float* e_a    = p; p += BH_ * L_;
  float* sumQ   = p; p += BH_ * NC_ * DH_;
  float* sumK   = p; p += BH_ * NC_ * DH_;
  float* sumQSI = p; p += BH_ * NC_ * DH_;
  float* sumKSO = p; p += BH_ * NC_ * DH_;
  float* sumE   = p; p += BH_ * NC_;

  proj3_k<<<dim3(BL_ / 64, D_ / 64, 3), 256, 0, stream>>>(
      queries, keys, values, Wq, bq, Wk, bk, Wv, bv, Qb, Kb, Vb, sumQ, sumK);
  flow_phase1_k<<<BH_ * NC_, 64, 0, stream>>>(Qb, Kb, sumQ, sumK,
                                              qscale, si_a, so_a, sumQSI, sumKSO);
  flow_phase2_k<<<BH_ * NC_, 64, 0, stream>>>(Qb, Kb, sumQSI, sumKSO, si_a, so_a,
                                              salloc, e_a, sumE);
  flow_ckv_k<<<BH_ * NC_, 256, 0, stream>>>(Kb, Vb, e_a, sumE, comp, KVb);
  kv_prefix_k<<<BH_, 256, 0, stream>>>(KVb);
  attn_k<<<BH_ * NC_, 256, 0, stream>>>(Qb, Kb, Vb, KVb, qscale, salloc, comp, Xb);
  gemm_out_k<<<dim3(BL_ / 64, D_ / 64), 256, 0, stream>>>(Xb, Wo, bo, (float*)d_out);
}